// Round 8
// baseline (42.491 us; speedup 1.0000x reference)
//
#include <hip/hip_runtime.h>
#include <math.h>

#define HH 512
#define WH 512
#define L2E 1.44269504f
#define PI_F 3.14159265358979323846f
#define FTK 72   // K stride in shorts (144 B): 16B-aligned, conflict-free b128 frag reads

typedef __attribute__((ext_vector_type(8))) short short8v;
typedef __attribute__((ext_vector_type(4))) float float4v;

// Offsets (dy,dx) in 9x9 window, ring-ordered by r2=dy^2+dx^2, truncated to 64:
// entries past index 48 have r2>=17 > R_MAX^2=16 -> never active for ANY input
// (Rsq = clip(2*max(sx,sy),1,4)^2 <= 16). Encoded ((dy+4)<<4)|(dx+4).
// Chunk1 (k>=32) first entry r2=10 -> chunk1 needed iff Rsq>=10.
__device__ const unsigned char ORD[64] = {
    0x44,                                     // r2=0
    0x34,0x43,0x45,0x54,                      // r2=1
    0x33,0x35,0x53,0x55,                      // r2=2
    0x24,0x42,0x46,0x64,                      // r2=4
    0x23,0x25,0x32,0x36,0x52,0x56,0x63,0x65,  // r2=5
    0x22,0x26,0x62,0x66,                      // r2=8
    0x14,0x41,0x47,0x74,                      // r2=9
    0x13,0x15,0x31,0x37,0x51,0x57,0x73,0x75,  // r2=10
    0x12,0x16,0x21,0x27,0x61,0x67,0x72,0x76,  // r2=13
    0x04,0x40,0x48,0x84,                      // r2=16  -> nact<=49
    0x03,0x05,0x30,0x38,0x50,0x58,0x83,0x85,  // r2=17 (padding, never active)
    0x11,0x17,0x71,0x77,                      // r2=18
    0x02,0x06,0x20                            // r2=20
};

// ws layout:
//   glr:   [1024][4] f32    at float offset 0     (16 KB)
//   featT: [1024][128] bf16 at float offset 4096  (256 KB), cell-major
__global__ __launch_bounds__(256) void prep_kernel(
    const float* __restrict__ feat,   // [128][32][32]
    const float* __restrict__ guide,  // [3][512][512]
    float* __restrict__ ws)
{
    const int gid = blockIdx.x * 256 + threadIdx.x;
    float* glr = ws;
    unsigned short* featT = (unsigned short*)(ws + 4096);
    if (gid < 131072) {
        const int cell = gid >> 7;
        const int c    = gid & 127;
        const float v  = feat[c * 1024 + cell];
        const unsigned int b = __float_as_uint(v);
        featT[gid] = (unsigned short)((b + 0x7FFFu + ((b >> 16) & 1u)) >> 16);  // rne bf16
    }
    if (gid < 1024) {
        const int u = gid >> 5, v = gid & 31;
        // bilinear downsample at SCALE=16 == 2x2 average at (16u+7, 16v+7)
        const int y0 = u * 16 + 7, x0 = v * 16 + 7;
        #pragma unroll
        for (int ch = 0; ch < 3; ++ch) {
            const float* g = guide + ch * (HH * WH);
            const float s = g[y0 * WH + x0] + g[y0 * WH + x0 + 1]
                          + g[(y0 + 1) * WH + x0] + g[(y0 + 1) * WH + x0 + 1];
            glr[gid * 4 + ch] = 0.25f * s;
        }
        glr[gid * 4 + 3] = 0.0f;
    }
}

// 512 blocks = 512 cell-PAIRS (2 adjacent cells = 32x16 px), 512 threads = 8 waves.
// Wave w: cell c2 = w>>2, pixel rows (w&3)*4 .. +3. Per-wave work identical to r5.
// Stores go through an LDS transpose so every global store instruction emits
// 8 x 128B fully-contiguous segments (complete L2 lines, no cross-block merge).
__global__ __launch_bounds__(512, 4) void jbu_kernel(
    const float* __restrict__ guide,
    const float* __restrict__ sx_raw,
    const float* __restrict__ sy_raw,
    const float* __restrict__ th_raw,
    const float* __restrict__ sr_raw,
    const float* __restrict__ ws,
    float* __restrict__ out)
{
    __shared__ __align__(16) unsigned short FT[2][128][FTK];   // 36.9 KB [cell][ch][k]
    __shared__ float tabK[2][64], tabA[2][64], tabB[2][64];
    __shared__ float tabG0[2][64], tabG1[2][64], tabG2[2][64];
    __shared__ float hdr[2][8];
    __shared__ __align__(16) float OutT[16][16][34];           // 34.8 KB [row][ch16][px32+pad]

    const float* glr = ws;
    const unsigned short* featT = (const unsigned short*)(ws + 4096);

    const int tid = threadIdx.x;
    const int b   = blockIdx.x;
    // XCD swizzle (bijective, 512 % 8 == 0): xcd = b&7; consecutive pairs within
    // an XCD are horizontally adjacent 32px strips.
    const int pair = (b & 7) * 64 + (b >> 3);   // 0..511
    const int cu  = pair >> 4;                  // 0..31
    const int cv0 = (pair & 15) * 2;            // 0,2,..,30

    // ---- per-cell coefficient tables (2 cells x 64 ring k-slots), 2 waves ----
    if (tid < 128) {
        const int c2 = tid >> 6;
        const int k  = tid & 63;
        const int cell = cu * 32 + cv0 + c2;
        const float sx  = fmaxf(__expf(sx_raw[cell]), 1e-6f);
        const float sy  = fmaxf(__expf(sy_raw[cell]), 1e-6f);
        const float tr  = fminf(fmaxf(th_raw[cell], -10.f), 10.f);
        const float e2t = __expf(2.0f * tr);
        const float thv = PI_F * ((e2t - 1.0f) / (e2t + 1.0f));   // pi*tanh
        const float sr  = fmaxf(__expf(sr_raw[cell]), 1e-6f);
        const float R   = fminf(fmaxf(2.0f * fmaxf(sx, sy), 1.0f), 4.0f);
        const float Rsq = R * R;
        float sth, cth;
        __sincosf(thv, &sth, &cth);
        const float i2sx = 1.0f / (2.0f * sx * sx + 1e-8f);
        const float i2sy = 1.0f / (2.0f * sy * sy + 1e-8f);
        const float i2sr = 1.0f / (2.0f * sr * sr + 1e-8f);
        if (k == 0) {
            hdr[c2][0] = cth; hdr[c2][1] = sth;
            hdr[c2][2] = i2sx * L2E; hdr[c2][3] = i2sy * L2E; hdr[c2][4] = i2sr * L2E;
            hdr[c2][5] = Rsq;
        }
        const int o  = ORD[k];
        const int dy = (o >> 4) - 4, dx = (o & 15) - 4;
        const int cv = cv0 + c2;
        const int act = ((float)(dy * dy + dx * dx) <= Rsq);
        const int ui = min(max(cu + dy, 0), 31);
        const int vi = min(max(cv + dx, 0), 31);
        const float gl0 = glr[(ui * 32 + vi) * 4 + 0];
        const float gl1 = glr[(ui * 32 + vi) * 4 + 1];
        const float gl2 = glr[(ui * 32 + vi) * 4 + 2];
        const float rk = (float)(vi - cv), tk = (float)(ui - cu);
        const float ak = rk * cth + tk * sth;
        const float bk = tk * cth - rk * sth;
        tabK[c2][k]  = act ? -(ak * ak * i2sx + bk * bk * i2sy
                               + (gl0*gl0 + gl1*gl1 + gl2*gl2) * i2sr) * L2E
                           : -1e30f;
        tabA[c2][k]  = 2.0f * ak * i2sx * L2E;
        tabB[c2][k]  = 2.0f * bk * i2sy * L2E;
        tabG0[c2][k] = 2.0f * gl0 * i2sr * L2E;
        tabG1[c2][k] = 2.0f * gl1 * i2sr * L2E;
        tabG2[c2][k] = 2.0f * gl2 * i2sr * L2E;
    }

    // ---- per-wave ids + guide pixel loads ----
    const int wave = tid >> 6;
    const int lane = tid & 63;
    const int lg   = lane >> 4;       // k-group (A/B) / x-group (C/D)
    const int pxx  = lane & 15;       // A row (pixel x) / B col (channel slot)
    const int c2   = wave >> 2;
    const int mtb  = (wave & 3) * 4;  // this wave's 4 pixel rows
    const int cv   = cv0 + c2;

    float g0[4], g1[4], g2[4];
    #pragma unroll
    for (int mt = 0; mt < 4; ++mt) {
        const int y = cu * 16 + mtb + mt;
        const int o = y * WH + cv * 16 + pxx;
        g0[mt] = guide[o];
        g1[mt] = guide[HH * WH + o];
        g2[mt] = guide[2 * HH * WH + o];
    }

    // ---- stage FT[c2][ch][k] from featT (L2-hot, 16B loads); k fastest ----
    #pragma unroll
    for (int it = 0; it < 4; ++it) {
        const int item = it * 512 + tid;       // 2048 = 2 c2 * 16 cg * 64 k
        const int k   = item & 63;
        const int cg  = (item >> 6) & 15;
        const int c2s = item >> 10;
        const int o  = ORD[k];
        const int ui = min(max(cu + (o >> 4) - 4, 0), 31);
        const int vi = min(max(cv0 + c2s + (o & 15) - 4, 0), 31);
        const uint4 val = *(const uint4*)(featT + (ui * 32 + vi) * 128 + cg * 8);
        const unsigned short* vs = (const unsigned short*)&val;
        #pragma unroll
        for (int j = 0; j < 8; ++j)
            FT[c2s][cg * 8 + j][k] = vs[j];
    }
    __syncthreads();

    const float cth = hdr[c2][0], sth = hdr[c2][1];
    const float i2sxl = hdr[c2][2], i2syl = hdr[c2][3], i2srl = hdr[c2][4];
    const bool  use2 = (hdr[0][5] >= 10.0f) || (hdr[1][5] >= 10.0f);  // block-uniform
    const float qd = ((float)pxx - 7.5f) * 0.0625f;

    float a0[4], b0[4], P[4];
    #pragma unroll
    for (int mt = 0; mt < 4; ++mt) {
        const float pd = ((float)(mtb + mt) - 7.5f) * 0.0625f;
        a0[mt] = qd * cth + pd * sth;
        b0[mt] = pd * cth - qd * sth;
        P[mt]  = -(a0[mt]*a0[mt]*i2sxl + b0[mt]*b0[mt]*i2syl
                   + (g0[mt]*g0[mt] + g1[mt]*g1[mt] + g2[mt]*g2[mt]) * i2srl);
    }

    // ---- weight gen into A fragments (lane: row=pxx, k=ks*32+lg*8+i) ----
    short8v Afrag[4][2];
    float den[4] = {0.f, 0.f, 0.f, 0.f};
    #pragma unroll
    for (int ks = 0; ks < 2; ++ks) {
        if (ks == 0 || use2) {
            float cK[8], cA[8], cB[8], cG0[8], cG1[8], cG2[8];
            #pragma unroll
            for (int i = 0; i < 8; ++i) {
                const int k = ks * 32 + lg * 8 + i;
                cK[i] = tabK[c2][k];  cA[i] = tabA[c2][k];  cB[i] = tabB[c2][k];
                cG0[i] = tabG0[c2][k]; cG1[i] = tabG1[c2][k]; cG2[i] = tabG2[c2][k];
            }
            #pragma unroll
            for (int mt = 0; mt < 4; ++mt) {
                short8v av;
                #pragma unroll
                for (int i = 0; i < 8; ++i) {
                    float lw = P[mt] + cK[i];
                    lw = fmaf(a0[mt], cA[i], lw);
                    lw = fmaf(b0[mt], cB[i], lw);
                    lw = fmaf(g0[mt], cG0[i], lw);
                    lw = fmaf(g1[mt], cG1[i], lw);
                    lw = fmaf(g2[mt], cG2[i], lw);
                    const float w = __builtin_amdgcn_exp2f(lw);
                    den[mt] += w;
                    const unsigned int bb = __float_as_uint(w);
                    av[i] = (short)((bb + 0x7FFFu + ((bb >> 16) & 1u)) >> 16);
                }
                Afrag[mt][ks] = av;
            }
        }
    }

    // ---- den reduce over 4 k-groups, redistribute to C-row owners ----
    float invd[4][4];
    #pragma unroll
    for (int mt = 0; mt < 4; ++mt) {
        float d = den[mt];
        d += __shfl_xor(d, 16);
        d += __shfl_xor(d, 32);
        const float id = 1.0f / fmaxf(d, 1e-8f);
        #pragma unroll
        for (int r = 0; r < 4; ++r)
            invd[mt][r] = __shfl(id, lg * 4 + r);   // den of x-pixel lg*4+r
    }

    // ---- MFMA -> LDS transpose -> 128B-contiguous stores, per 16-ch tile ----
    const int pxq   = tid & 7;          // store phase: x-quad (0..7 -> 32 px)
    const int pr    = tid >> 3;         // store phase: (ch, row-quad) pair 0..63
    const int chs   = pr & 15;
    const int rowq  = pr >> 4;          // 0..3
    #pragma unroll
    for (int nt = 0; nt < 8; ++nt) {
        const int ch = nt * 16 + pxx;
        short8v Bf0 = *(const short8v*)&FT[c2][ch][lg * 8];
        short8v Bf1 = *(const short8v*)&FT[c2][ch][32 + lg * 8];
        #pragma unroll
        for (int mt = 0; mt < 4; ++mt) {
            float4v acc = {0.f, 0.f, 0.f, 0.f};
            acc = __builtin_amdgcn_mfma_f32_16x16x32_bf16(Afrag[mt][0], Bf0, acc, 0, 0, 0);
            if (use2)
                acc = __builtin_amdgcn_mfma_f32_16x16x32_bf16(Afrag[mt][1], Bf1, acc, 0, 0, 0);
            float4v res;
            res[0] = acc[0] * invd[mt][0];
            res[1] = acc[1] * invd[mt][1];
            res[2] = acc[2] * invd[mt][2];
            res[3] = acc[3] * invd[mt][3];
            *(float4v*)&OutT[mtb + mt][pxx][c2 * 16 + lg * 4] = res;
        }
        __syncthreads();
        // cooperative store: per instruction 8 x (ch,row) pairs x 128B contiguous
        #pragma unroll
        for (int i = 0; i < 4; ++i) {
            const int row = i * 4 + rowq;
            const float4v v = *(const float4v*)&OutT[row][chs][pxq * 4];
            *(float4v*)(out + (size_t)(nt * 16 + chs) * (HH * WH)
                        + (cu * 16 + row) * WH + cv0 * 16 + pxq * 4) = v;
        }
        __syncthreads();
    }
}

extern "C" void kernel_launch(void* const* d_in, const int* in_sizes, int n_in,
                              void* d_out, int out_size, void* d_ws, size_t ws_size,
                              hipStream_t stream) {
    const float* feat   = (const float*)d_in[0];
    const float* guide  = (const float*)d_in[1];
    const float* sx_raw = (const float*)d_in[2];
    const float* sy_raw = (const float*)d_in[3];
    const float* th_raw = (const float*)d_in[4];
    const float* sr_raw = (const float*)d_in[5];
    float* out = (float*)d_out;
    float* ws  = (float*)d_ws;

    prep_kernel<<<512, 256, 0, stream>>>(feat, guide, ws);
    jbu_kernel<<<512, 512, 0, stream>>>(guide, sx_raw, sy_raw, th_raw, sr_raw, ws, out);
}

// Round 9
// 37.286 us; speedup vs baseline: 1.1396x; 1.1396x over previous
//
#include <hip/hip_runtime.h>
#include <math.h>

#define HH 512
#define WH 512
#define L2E 1.44269504f
#define PI_F 3.14159265358979323846f
#define FTK 72   // K stride in shorts (144 B): 16B-aligned; b128 frag reads conflict-free

typedef __attribute__((ext_vector_type(8))) short short8v;
typedef __attribute__((ext_vector_type(4))) float float4v;

// Offsets (dy,dx) in 9x9 window, ring-ordered by r2=dy^2+dx^2, truncated to 64:
// entries past index 48 have r2>=17 > R_MAX^2=16 -> never active for ANY input
// (Rsq = clip(2*max(sx,sy),1,4)^2 <= 16). Encoded ((dy+4)<<4)|(dx+4).
// Chunk1 (k>=32) first entry r2=10 -> chunk1 needed iff Rsq>=10.
__device__ const unsigned char ORD[64] = {
    0x44,                                     // r2=0
    0x34,0x43,0x45,0x54,                      // r2=1
    0x33,0x35,0x53,0x55,                      // r2=2
    0x24,0x42,0x46,0x64,                      // r2=4
    0x23,0x25,0x32,0x36,0x52,0x56,0x63,0x65,  // r2=5
    0x22,0x26,0x62,0x66,                      // r2=8
    0x14,0x41,0x47,0x74,                      // r2=9
    0x13,0x15,0x31,0x37,0x51,0x57,0x73,0x75,  // r2=10
    0x12,0x16,0x21,0x27,0x61,0x67,0x72,0x76,  // r2=13
    0x04,0x40,0x48,0x84,                      // r2=16  -> nact<=49
    0x03,0x05,0x30,0x38,0x50,0x58,0x83,0x85,  // r2=17 (padding, never active)
    0x11,0x17,0x71,0x77,                      // r2=18
    0x02,0x06,0x20                            // r2=20
};

// Fully fused: one cell (16x16 px) per block, all 128 channels, 256 threads = 4 waves.
// Wave w owns pixel rows w*4..w*4+3 (each = one 16x16x32-MFMA M-tile).
// lw = P(pixel) + K(k) + a0*A + b0*B + g0*G0 + g1*G1 + g2*G2, pre-scaled by log2e.
// Staging reads feat directly (L2-hot 512 KB): thread owns ONE k-cell, marches
// 32 channels (single ORD decode; 32 independent scalar loads, ILP-covered).
__global__ __launch_bounds__(256, 4) void jbu_fused_kernel(
    const float* __restrict__ feat,    // [128][32][32]
    const float* __restrict__ guide,   // [3][512][512]
    const float* __restrict__ sx_raw,
    const float* __restrict__ sy_raw,
    const float* __restrict__ th_raw,
    const float* __restrict__ sr_raw,
    float* __restrict__ out)           // [128][512][512]
{
    __shared__ __align__(16) unsigned short FT[128 * FTK];   // 18.4 KB [ch][k]
    __shared__ float tabK[64], tabA[64], tabB[64];
    __shared__ float tabG0[64], tabG1[64], tabG2[64];
    __shared__ float hdr[6];

    const int tid = threadIdx.x;
    const int b   = blockIdx.x;
    // XCD swizzle (bijective, 1024 % 8 == 0): xcd = b&7; consecutive cells within
    // an XCD are horizontally adjacent -> sibling 64B line-halves merge in L2.
    const int cell = (b & 7) * 128 + (b >> 3);   // 0..1023
    const int cu = cell >> 5, cv = cell & 31;

    // ---- per-cell coefficient table (64 ring-ordered k-slots), wave 0 ----
    if (tid < 64) {
        const int k = tid;
        const float sx  = fmaxf(__expf(sx_raw[cell]), 1e-6f);
        const float sy  = fmaxf(__expf(sy_raw[cell]), 1e-6f);
        const float tr  = fminf(fmaxf(th_raw[cell], -10.f), 10.f);
        const float e2t = __expf(2.0f * tr);
        const float thv = PI_F * ((e2t - 1.0f) / (e2t + 1.0f));   // pi*tanh
        const float sr  = fmaxf(__expf(sr_raw[cell]), 1e-6f);
        const float R   = fminf(fmaxf(2.0f * fmaxf(sx, sy), 1.0f), 4.0f);
        const float Rsq = R * R;
        float sth, cth;
        __sincosf(thv, &sth, &cth);
        const float i2sx = 1.0f / (2.0f * sx * sx + 1e-8f);
        const float i2sy = 1.0f / (2.0f * sy * sy + 1e-8f);
        const float i2sr = 1.0f / (2.0f * sr * sr + 1e-8f);
        if (k == 0) {
            hdr[0] = cth; hdr[1] = sth;
            hdr[2] = i2sx * L2E; hdr[3] = i2sy * L2E; hdr[4] = i2sr * L2E;
            hdr[5] = Rsq;
        }
        const int o  = ORD[k];
        const int dy = (o >> 4) - 4, dx = (o & 15) - 4;
        const int act = ((float)(dy * dy + dx * dx) <= Rsq);
        const int ui = min(max(cu + dy, 0), 31);
        const int vi = min(max(cv + dx, 0), 31);
        // guide_lr(ui,vi): bilinear down at SCALE=16 == 2x2 avg at (16u+7,16v+7)
        const int yg = ui * 16 + 7, xg = vi * 16 + 7;
        float gl[3];
        #pragma unroll
        for (int ch = 0; ch < 3; ++ch) {
            const float* g = guide + ch * (HH * WH);
            gl[ch] = 0.25f * (g[yg * WH + xg] + g[yg * WH + xg + 1]
                            + g[(yg + 1) * WH + xg] + g[(yg + 1) * WH + xg + 1]);
        }
        const float rk = (float)(vi - cv), tk = (float)(ui - cu);
        const float ak = rk * cth + tk * sth;
        const float bk = tk * cth - rk * sth;
        tabK[k]  = act ? -(ak * ak * i2sx + bk * bk * i2sy
                           + (gl[0]*gl[0] + gl[1]*gl[1] + gl[2]*gl[2]) * i2sr) * L2E
                       : -1e30f;
        tabA[k]  = 2.0f * ak * i2sx * L2E;
        tabB[k]  = 2.0f * bk * i2sy * L2E;
        tabG0[k] = 2.0f * gl[0] * i2sr * L2E;
        tabG1[k] = 2.0f * gl[1] * i2sr * L2E;
        tabG2[k] = 2.0f * gl[2] * i2sr * L2E;
    }

    // ---- per-wave ids + guide pixel loads (issue early) ----
    const int wave = tid >> 6;
    const int lane = tid & 63;
    const int lg   = lane >> 4;       // k-group (A/B) / x-group (C/D)
    const int pxx  = lane & 15;       // A row (pixel x) / B col (channel slot)
    const int mtb  = wave * 4;        // this wave's 4 pixel rows

    float g0[4], g1[4], g2[4];
    #pragma unroll
    for (int mt = 0; mt < 4; ++mt) {
        const int y = cu * 16 + mtb + mt;
        const int o = y * WH + cv * 16 + pxx;
        g0[mt] = guide[o];
        g1[mt] = guide[HH * WH + o];
        g2[mt] = guide[2 * HH * WH + o];
    }

    // ---- fused staging: FT[ch][k] = bf16(feat[ch][cell(k)]), 32 ch/thread ----
    {
        const int k  = tid & 63;
        const int cb = (tid >> 6) * 32;          // channel base for this thread
        const int o  = ORD[k];
        const int ui = min(max(cu + (o >> 4) - 4, 0), 31);
        const int vi = min(max(cv + (o & 15) - 4, 0), 31);
        const float* fp = feat + ui * 32 + vi;
        #pragma unroll
        for (int j = 0; j < 32; ++j) {
            const float fv = fp[(cb + j) * 1024];
            const unsigned int bb = __float_as_uint(fv);
            FT[(cb + j) * FTK + k] =
                (unsigned short)((bb + 0x7FFFu + ((bb >> 16) & 1u)) >> 16);  // rne bf16
        }
    }
    __syncthreads();

    const float cth = hdr[0], sth = hdr[1];
    const float i2sxl = hdr[2], i2syl = hdr[3], i2srl = hdr[4];
    const bool  use2 = hdr[5] >= 10.0f;   // chunk1 (k>=32) has any active offset
    const float qd = ((float)pxx - 7.5f) * 0.0625f;

    float a0[4], b0[4], P[4];
    #pragma unroll
    for (int mt = 0; mt < 4; ++mt) {
        const float pd = ((float)(mtb + mt) - 7.5f) * 0.0625f;
        a0[mt] = qd * cth + pd * sth;
        b0[mt] = pd * cth - qd * sth;
        P[mt]  = -(a0[mt]*a0[mt]*i2sxl + b0[mt]*b0[mt]*i2syl
                   + (g0[mt]*g0[mt] + g1[mt]*g1[mt] + g2[mt]*g2[mt]) * i2srl);
    }

    // ---- weight gen into A fragments (lane: row=pxx, k=ks*32+lg*8+i) ----
    short8v Afrag[4][2];
    float den[4] = {0.f, 0.f, 0.f, 0.f};
    #pragma unroll
    for (int ks = 0; ks < 2; ++ks) {
        if (ks == 0 || use2) {
            float cK[8], cA[8], cB[8], cG0[8], cG1[8], cG2[8];
            #pragma unroll
            for (int i = 0; i < 8; ++i) {
                const int k = ks * 32 + lg * 8 + i;
                cK[i] = tabK[k];  cA[i] = tabA[k];  cB[i] = tabB[k];
                cG0[i] = tabG0[k]; cG1[i] = tabG1[k]; cG2[i] = tabG2[k];
            }
            #pragma unroll
            for (int mt = 0; mt < 4; ++mt) {
                short8v av;
                #pragma unroll
                for (int i = 0; i < 8; ++i) {
                    float lw = P[mt] + cK[i];
                    lw = fmaf(a0[mt], cA[i], lw);
                    lw = fmaf(b0[mt], cB[i], lw);
                    lw = fmaf(g0[mt], cG0[i], lw);
                    lw = fmaf(g1[mt], cG1[i], lw);
                    lw = fmaf(g2[mt], cG2[i], lw);
                    const float w = __builtin_amdgcn_exp2f(lw);
                    den[mt] += w;
                    const unsigned int bb = __float_as_uint(w);
                    av[i] = (short)((bb + 0x7FFFu + ((bb >> 16) & 1u)) >> 16);
                }
                Afrag[mt][ks] = av;
            }
        }
    }

    // ---- den reduce over 4 k-groups, redistribute to C-row owners ----
    float invd[4][4];
    #pragma unroll
    for (int mt = 0; mt < 4; ++mt) {
        float d = den[mt];
        d += __shfl_xor(d, 16);
        d += __shfl_xor(d, 32);
        const float id = 1.0f / fmaxf(d, 1e-8f);
        #pragma unroll
        for (int r = 0; r < 4; ++r)
            invd[mt][r] = __shfl(id, lg * 4 + r);   // den of x-pixel lg*4+r
    }

    // ---- MFMA + store per 16-channel tile (8 tiles = 128 ch) ----
    #pragma unroll
    for (int nt = 0; nt < 8; ++nt) {
        const int ch = nt * 16 + pxx;
        short8v Bf0 = *(const short8v*)&FT[ch * FTK + lg * 8];
        short8v Bf1 = *(const short8v*)&FT[ch * FTK + 32 + lg * 8];
        const size_t chp = (size_t)ch * (HH * WH);
        #pragma unroll
        for (int mt = 0; mt < 4; ++mt) {
            float4v acc = {0.f, 0.f, 0.f, 0.f};
            acc = __builtin_amdgcn_mfma_f32_16x16x32_bf16(Afrag[mt][0], Bf0, acc, 0, 0, 0);
            if (use2)
                acc = __builtin_amdgcn_mfma_f32_16x16x32_bf16(Afrag[mt][1], Bf1, acc, 0, 0, 0);
            const int y = cu * 16 + mtb + mt;
            float4v res;
            res[0] = acc[0] * invd[mt][0];
            res[1] = acc[1] * invd[mt][1];
            res[2] = acc[2] * invd[mt][2];
            res[3] = acc[3] * invd[mt][3];
            *(float4v*)(out + chp + y * WH + cv * 16 + lg * 4) = res;
        }
    }
}

extern "C" void kernel_launch(void* const* d_in, const int* in_sizes, int n_in,
                              void* d_out, int out_size, void* d_ws, size_t ws_size,
                              hipStream_t stream) {
    const float* feat   = (const float*)d_in[0];
    const float* guide  = (const float*)d_in[1];
    const float* sx_raw = (const float*)d_in[2];
    const float* sy_raw = (const float*)d_in[3];
    const float* th_raw = (const float*)d_in[4];
    const float* sr_raw = (const float*)d_in[5];
    float* out = (float*)d_out;
    (void)d_ws; (void)ws_size;

    jbu_fused_kernel<<<1024, 256, 0, stream>>>(feat, guide, sx_raw, sy_raw,
                                               th_raw, sr_raw, out);
}

// Round 10
// 37.184 us; speedup vs baseline: 1.1427x; 1.0027x over previous
//
#include <hip/hip_runtime.h>
#include <math.h>

#define HH 512
#define WH 512
#define L2E 1.44269504f
#define PI_F 3.14159265358979323846f
#define FTK 72   // K stride in shorts (144 B): 16B-aligned; b128 frag reads conflict-free

typedef __attribute__((ext_vector_type(8))) short short8v;
typedef __attribute__((ext_vector_type(4))) float float4v;

// Offsets (dy,dx) in 9x9 window, ring-ordered by r2=dy^2+dx^2, truncated to 64:
// entries past index 48 have r2>=17 > R_MAX^2=16 -> never active for ANY input
// (Rsq = clip(2*max(sx,sy),1,4)^2 <= 16). Encoded ((dy+4)<<4)|(dx+4).
// Chunk1 (k>=32) first entry r2=10 -> chunk1 needed iff Rsq>=10.
__device__ const unsigned char ORD[64] = {
    0x44,                                     // r2=0
    0x34,0x43,0x45,0x54,                      // r2=1
    0x33,0x35,0x53,0x55,                      // r2=2
    0x24,0x42,0x46,0x64,                      // r2=4
    0x23,0x25,0x32,0x36,0x52,0x56,0x63,0x65,  // r2=5
    0x22,0x26,0x62,0x66,                      // r2=8
    0x14,0x41,0x47,0x74,                      // r2=9
    0x13,0x15,0x31,0x37,0x51,0x57,0x73,0x75,  // r2=10
    0x12,0x16,0x21,0x27,0x61,0x67,0x72,0x76,  // r2=13
    0x04,0x40,0x48,0x84,                      // r2=16  -> nact<=49
    0x03,0x05,0x30,0x38,0x50,0x58,0x83,0x85,  // r2=17 (padding, never active)
    0x11,0x17,0x71,0x77,                      // r2=18
    0x02,0x06,0x20                            // r2=20
};

// Fully fused. 512 blocks = 512 cell-PAIRS (32x16 px strip), 512 threads = 8 waves.
// Wave w owns pixel rows {2w, 2w+1} of BOTH cells -> after the left/right MFMAs,
// each lane's two dwordx4 stores complete a full 128B line intra-wave (no
// cross-block L2-merge timing dependence, no extra barriers).
// lw = P(pixel) + K(k) + a0*A + b0*B + g0*G0 + g1*G1 + g2*G2, pre-scaled by log2e.
__global__ __launch_bounds__(512, 4) void jbu_pair_kernel(
    const float* __restrict__ feat,    // [128][32][32]
    const float* __restrict__ guide,   // [3][512][512]
    const float* __restrict__ sx_raw,
    const float* __restrict__ sy_raw,
    const float* __restrict__ th_raw,
    const float* __restrict__ sr_raw,
    float* __restrict__ out)           // [128][512][512]
{
    __shared__ __align__(16) unsigned short FT[2 * 128 * FTK];   // 36.9 KB [c2][ch][k]
    __shared__ float tabK[2][64], tabA[2][64], tabB[2][64];
    __shared__ float tabG0[2][64], tabG1[2][64], tabG2[2][64];
    __shared__ float hdr[2][8];

    const int tid = threadIdx.x;
    const int b   = blockIdx.x;
    // XCD swizzle (bijective, 512 % 8 == 0): xcd = b&7; consecutive pairs within
    // an XCD are horizontally adjacent strips -> read locality in L2.
    const int pair = (b & 7) * 64 + (b >> 3);   // 0..511
    const int cu  = pair >> 4;                  // 0..31
    const int cv0 = (pair & 15) * 2;            // 0,2,..,30

    // ---- per-cell coefficient tables (2 cells x 64 ring k-slots), 2 waves ----
    if (tid < 128) {
        const int c2 = tid >> 6;
        const int k  = tid & 63;
        const int cv = cv0 + c2;
        const int cell = cu * 32 + cv;
        const float sx  = fmaxf(__expf(sx_raw[cell]), 1e-6f);
        const float sy  = fmaxf(__expf(sy_raw[cell]), 1e-6f);
        const float tr  = fminf(fmaxf(th_raw[cell], -10.f), 10.f);
        const float e2t = __expf(2.0f * tr);
        const float thv = PI_F * ((e2t - 1.0f) / (e2t + 1.0f));   // pi*tanh
        const float sr  = fmaxf(__expf(sr_raw[cell]), 1e-6f);
        const float R   = fminf(fmaxf(2.0f * fmaxf(sx, sy), 1.0f), 4.0f);
        const float Rsq = R * R;
        float sth, cth;
        __sincosf(thv, &sth, &cth);
        const float i2sx = 1.0f / (2.0f * sx * sx + 1e-8f);
        const float i2sy = 1.0f / (2.0f * sy * sy + 1e-8f);
        const float i2sr = 1.0f / (2.0f * sr * sr + 1e-8f);
        if (k == 0) {
            hdr[c2][0] = cth; hdr[c2][1] = sth;
            hdr[c2][2] = i2sx * L2E; hdr[c2][3] = i2sy * L2E; hdr[c2][4] = i2sr * L2E;
            hdr[c2][5] = Rsq;
        }
        const int o  = ORD[k];
        const int dy = (o >> 4) - 4, dx = (o & 15) - 4;
        const int act = ((float)(dy * dy + dx * dx) <= Rsq);
        const int ui = min(max(cu + dy, 0), 31);
        const int vi = min(max(cv + dx, 0), 31);
        // guide_lr(ui,vi): bilinear down at SCALE=16 == 2x2 avg at (16u+7,16v+7)
        const int yg = ui * 16 + 7, xg = vi * 16 + 7;
        float gl[3];
        #pragma unroll
        for (int ch = 0; ch < 3; ++ch) {
            const float* g = guide + ch * (HH * WH);
            gl[ch] = 0.25f * (g[yg * WH + xg] + g[yg * WH + xg + 1]
                            + g[(yg + 1) * WH + xg] + g[(yg + 1) * WH + xg + 1]);
        }
        const float rk = (float)(vi - cv), tk = (float)(ui - cu);
        const float ak = rk * cth + tk * sth;
        const float bk = tk * cth - rk * sth;
        tabK[c2][k]  = act ? -(ak * ak * i2sx + bk * bk * i2sy
                               + (gl[0]*gl[0] + gl[1]*gl[1] + gl[2]*gl[2]) * i2sr) * L2E
                           : -1e30f;
        tabA[c2][k]  = 2.0f * ak * i2sx * L2E;
        tabB[c2][k]  = 2.0f * bk * i2sy * L2E;
        tabG0[c2][k] = 2.0f * gl[0] * i2sr * L2E;
        tabG1[c2][k] = 2.0f * gl[1] * i2sr * L2E;
        tabG2[c2][k] = 2.0f * gl[2] * i2sr * L2E;
    }

    // ---- per-wave ids + guide pixel loads (issue early) ----
    const int wave = tid >> 6;        // 0..7
    const int lane = tid & 63;
    const int lg   = lane >> 4;       // k-group (A/B) / x-quad (C/D)
    const int pxx  = lane & 15;       // A row (pixel x within cell) / B col (ch slot)
    const int mtb  = wave * 2;        // this wave's 2 pixel rows

    float g0[2][2], g1[2][2], g2[2][2];
    #pragma unroll
    for (int mt = 0; mt < 2; ++mt) {
        const int y = cu * 16 + mtb + mt;
        #pragma unroll
        for (int c2 = 0; c2 < 2; ++c2) {
            const int o = y * WH + (cv0 + c2) * 16 + pxx;
            g0[mt][c2] = guide[o];
            g1[mt][c2] = guide[HH * WH + o];
            g2[mt][c2] = guide[2 * HH * WH + o];
        }
    }

    // ---- fused staging: FT[c2][ch][k] = bf16(feat[ch][cell(c2,k)]), 32 ch/thread ----
    {
        const int k  = tid & 63;
        const int c2 = (tid >> 6) & 1;
        const int cb = (tid >> 7) * 32;          // channel base: 0/32/64/96
        const int o  = ORD[k];
        const int ui = min(max(cu + (o >> 4) - 4, 0), 31);
        const int vi = min(max(cv0 + c2 + (o & 15) - 4, 0), 31);
        const float* fp = feat + ui * 32 + vi;
        unsigned short* ft = &FT[(c2 * 128) * FTK + k];
        #pragma unroll
        for (int j = 0; j < 32; ++j) {
            const float fv = fp[(cb + j) * 1024];
            const unsigned int bb = __float_as_uint(fv);
            ft[(cb + j) * FTK] =
                (unsigned short)((bb + 0x7FFFu + ((bb >> 16) & 1u)) >> 16);  // rne bf16
        }
    }
    __syncthreads();

    const bool use2 = (hdr[0][5] >= 10.0f) || (hdr[1][5] >= 10.0f);  // block-uniform
    const float qd = ((float)pxx - 7.5f) * 0.0625f;  // same for both cells (own center)

    float a0[2][2], b0[2][2], P[2][2];
    #pragma unroll
    for (int c2 = 0; c2 < 2; ++c2) {
        const float cth = hdr[c2][0], sth = hdr[c2][1];
        const float i2sxl = hdr[c2][2], i2syl = hdr[c2][3], i2srl = hdr[c2][4];
        #pragma unroll
        for (int mt = 0; mt < 2; ++mt) {
            const float pd = ((float)(mtb + mt) - 7.5f) * 0.0625f;
            a0[mt][c2] = qd * cth + pd * sth;
            b0[mt][c2] = pd * cth - qd * sth;
            P[mt][c2]  = -(a0[mt][c2]*a0[mt][c2]*i2sxl + b0[mt][c2]*b0[mt][c2]*i2syl
                           + (g0[mt][c2]*g0[mt][c2] + g1[mt][c2]*g1[mt][c2]
                              + g2[mt][c2]*g2[mt][c2]) * i2srl);
        }
    }

    // ---- weight gen into A fragments (lane: row=pxx, k=ks*32+lg*8+i) ----
    short8v Afrag[2][2][2];           // [mt][c2][ks]
    float den[2][2] = {{0.f, 0.f}, {0.f, 0.f}};
    #pragma unroll
    for (int ks = 0; ks < 2; ++ks) {
        if (ks == 0 || use2) {
            #pragma unroll
            for (int c2 = 0; c2 < 2; ++c2) {
                float cK[8], cA[8], cB[8], cG0[8], cG1[8], cG2[8];
                #pragma unroll
                for (int i = 0; i < 8; ++i) {
                    const int k = ks * 32 + lg * 8 + i;
                    cK[i] = tabK[c2][k];  cA[i] = tabA[c2][k];  cB[i] = tabB[c2][k];
                    cG0[i] = tabG0[c2][k]; cG1[i] = tabG1[c2][k]; cG2[i] = tabG2[c2][k];
                }
                #pragma unroll
                for (int mt = 0; mt < 2; ++mt) {
                    short8v av;
                    #pragma unroll
                    for (int i = 0; i < 8; ++i) {
                        float lw = P[mt][c2] + cK[i];
                        lw = fmaf(a0[mt][c2], cA[i], lw);
                        lw = fmaf(b0[mt][c2], cB[i], lw);
                        lw = fmaf(g0[mt][c2], cG0[i], lw);
                        lw = fmaf(g1[mt][c2], cG1[i], lw);
                        lw = fmaf(g2[mt][c2], cG2[i], lw);
                        const float w = __builtin_amdgcn_exp2f(lw);
                        den[mt][c2] += w;
                        const unsigned int bb = __float_as_uint(w);
                        av[i] = (short)((bb + 0x7FFFu + ((bb >> 16) & 1u)) >> 16);
                    }
                    Afrag[mt][c2][ks] = av;
                }
            }
        }
    }

    // ---- den reduce over 4 k-groups, redistribute to C-row (x-quad) owners ----
    float invd[2][2][4];
    #pragma unroll
    for (int mt = 0; mt < 2; ++mt) {
        #pragma unroll
        for (int c2 = 0; c2 < 2; ++c2) {
            float d = den[mt][c2];
            d += __shfl_xor(d, 16);
            d += __shfl_xor(d, 32);
            const float id = 1.0f / fmaxf(d, 1e-8f);
            #pragma unroll
            for (int r = 0; r < 4; ++r)
                invd[mt][c2][r] = __shfl(id, lg * 4 + r);   // den of x-pixel lg*4+r
        }
    }

    // ---- MFMA + full-line stores per 16-channel tile ----
    #pragma unroll
    for (int nt = 0; nt < 8; ++nt) {
        const int ch = nt * 16 + pxx;
        short8v Bf0[2], Bf1[2];
        #pragma unroll
        for (int c2 = 0; c2 < 2; ++c2) {
            Bf0[c2] = *(const short8v*)&FT[(c2 * 128 + ch) * FTK + lg * 8];
            Bf1[c2] = *(const short8v*)&FT[(c2 * 128 + ch) * FTK + 32 + lg * 8];
        }
        const size_t chp = (size_t)ch * (HH * WH);
        #pragma unroll
        for (int mt = 0; mt < 2; ++mt) {
            const int y = cu * 16 + mtb + mt;
            float* rowp = out + chp + y * WH + cv0 * 16;
            float4v res[2];
            #pragma unroll
            for (int c2 = 0; c2 < 2; ++c2) {
                float4v acc = {0.f, 0.f, 0.f, 0.f};
                acc = __builtin_amdgcn_mfma_f32_16x16x32_bf16(
                    Afrag[mt][c2][0], Bf0[c2], acc, 0, 0, 0);
                if (use2)
                    acc = __builtin_amdgcn_mfma_f32_16x16x32_bf16(
                        Afrag[mt][c2][1], Bf1[c2], acc, 0, 0, 0);
                res[c2][0] = acc[0] * invd[mt][c2][0];
                res[c2][1] = acc[1] * invd[mt][c2][1];
                res[c2][2] = acc[2] * invd[mt][c2][2];
                res[c2][3] = acc[3] * invd[mt][c2][3];
            }
            // back-to-back 64B halves of the SAME 128B line (x 0-15 | x 16-31)
            *(float4v*)(rowp + lg * 4)      = res[0];
            *(float4v*)(rowp + 16 + lg * 4) = res[1];
        }
    }
}

extern "C" void kernel_launch(void* const* d_in, const int* in_sizes, int n_in,
                              void* d_out, int out_size, void* d_ws, size_t ws_size,
                              hipStream_t stream) {
    const float* feat   = (const float*)d_in[0];
    const float* guide  = (const float*)d_in[1];
    const float* sx_raw = (const float*)d_in[2];
    const float* sy_raw = (const float*)d_in[3];
    const float* th_raw = (const float*)d_in[4];
    const float* sr_raw = (const float*)d_in[5];
    float* out = (float*)d_out;
    (void)d_ws; (void)ws_size;

    jbu_pair_kernel<<<512, 512, 0, stream>>>(feat, guide, sx_raw, sy_raw,
                                             th_raw, sr_raw, out);
}